// Round 1
// baseline (3002.874 us; speedup 1.0000x reference)
//
#include <hip/hip_runtime.h>
#include <cstdint>
#include <cstddef>

#define HID 256

typedef __bf16 bf16;
typedef __bf16 bf16x4 __attribute__((ext_vector_type(4)));
typedef __bf16 bf16x8 __attribute__((ext_vector_type(8)));
typedef float f32x4 __attribute__((ext_vector_type(4)));

// ---------------- CSR build ----------------

__global__ void k_zero_i32(int* __restrict__ p, int n) {
  int i = blockIdx.x * blockDim.x + threadIdx.x;
  if (i < n) p[i] = 0;
}

__global__ void k_hist(const int* __restrict__ ei, int* __restrict__ deg, int E) {
  int i = blockIdx.x * blockDim.x + threadIdx.x;
  if (i < E) atomicAdd(&deg[ei[E + i]], 1);  // dst = ei[E + i]
}

__global__ void k_scan1(const int* __restrict__ deg, int* __restrict__ offs,
                        int* __restrict__ bsums, int n) {
  __shared__ int sh[1024];
  int i = blockIdx.x * 1024 + threadIdx.x;
  int v = (i < n) ? deg[i] : 0;
  sh[threadIdx.x] = v;
  __syncthreads();
  for (int d = 1; d < 1024; d <<= 1) {
    int t = (threadIdx.x >= (unsigned)d) ? sh[threadIdx.x - d] : 0;
    __syncthreads();
    sh[threadIdx.x] += t;
    __syncthreads();
  }
  if (i < n) offs[i] = sh[threadIdx.x] - v;  // exclusive within block
  if (threadIdx.x == 1023) bsums[blockIdx.x] = sh[1023];
}

__global__ void k_scan2(int* __restrict__ bsums, int nb) {
  if (threadIdx.x == 0 && blockIdx.x == 0) {
    int run = 0;
    for (int b = 0; b < nb; ++b) { int t = bsums[b]; bsums[b] = run; run += t; }
  }
}

__global__ void k_scan3(int* __restrict__ offs, int* __restrict__ cursor,
                        const int* __restrict__ bsums, int n, int E) {
  int i = blockIdx.x * 1024 + threadIdx.x;
  if (i < n) { int o = offs[i] + bsums[blockIdx.x]; offs[i] = o; cursor[i] = o; }
  if (i == 0) offs[n] = E;
}

__global__ void k_fill(const int* __restrict__ ei, int* __restrict__ cursor,
                       int* __restrict__ csr, int E) {
  int i = blockIdx.x * blockDim.x + threadIdx.x;
  if (i < E) {
    int pos = atomicAdd(&cursor[ei[E + i]], 1);
    csr[pos] = ei[i];  // store src, keyed by dst
  }
}

// ---------------- weight convert + input fc ----------------

__global__ void k_cvt(const float* __restrict__ s, bf16* __restrict__ d, int n) {
  int i = blockIdx.x * blockDim.x + threadIdx.x;
  if (i < n) d[i] = (bf16)s[i];
}

__global__ void k_input_fc(const float* __restrict__ x, const float* __restrict__ Win,
                           float* __restrict__ h, bf16* __restrict__ hb, int N) {
  int i = blockIdx.x;
  int c = threadIdx.x;
  float v = x[2 * i] * Win[2 * c] + x[2 * i + 1] * Win[2 * c + 1];
  size_t idx = (size_t)i * HID + c;
  h[idx] = v;
  hb[idx] = (bf16)v;
}

// ---------------- aggregation: one wave per node, CSR gather ----------------

__global__ __launch_bounds__(256) void k_aggregate(
    const bf16* __restrict__ hb, const int* __restrict__ offs,
    const int* __restrict__ csr, bf16* __restrict__ aggb,
    float* __restrict__ sums, int N) {
  // block 0 zeroes the BN-stat accumulators for the following GEMM
  if (blockIdx.x == 0 && threadIdx.x < 256) {
    sums[threadIdx.x] = 0.f;
    sums[256 + threadIdx.x] = 0.f;
  }
  int node = (int)((blockIdx.x * blockDim.x + threadIdx.x) >> 6);
  int lane = threadIdx.x & 63;
  if (node >= N) return;
  int e0 = offs[node], e1 = offs[node + 1];
  float a0 = 0.f, a1 = 0.f, a2 = 0.f, a3 = 0.f;
  int e = e0;
  for (; e + 1 < e1; e += 2) {  // 2-way unroll: two independent gathers in flight
    int s0 = csr[e], s1 = csr[e + 1];
    bf16x4 v0 = *(const bf16x4*)(hb + (size_t)s0 * HID + lane * 4);
    bf16x4 v1 = *(const bf16x4*)(hb + (size_t)s1 * HID + lane * 4);
    a0 += (float)v0[0] + (float)v1[0];
    a1 += (float)v0[1] + (float)v1[1];
    a2 += (float)v0[2] + (float)v1[2];
    a3 += (float)v0[3] + (float)v1[3];
  }
  if (e < e1) {
    int s0 = csr[e];
    bf16x4 v0 = *(const bf16x4*)(hb + (size_t)s0 * HID + lane * 4);
    a0 += (float)v0[0]; a1 += (float)v0[1]; a2 += (float)v0[2]; a3 += (float)v0[3];
  }
  bf16x4 o;
  o[0] = (bf16)a0; o[1] = (bf16)a1; o[2] = (bf16)a2; o[3] = (bf16)a3;
  *(bf16x4*)(aggb + (size_t)node * HID + lane * 4) = o;
}

// ---------------- fused layer GEMM: out = agg@Wr^T + h@Wo^T + br, + BN stats ----------------
// 128x128 tile, 4 waves (2x2), 16x16x32 bf16 MFMA, K = 2 phases x 256.

__global__ __launch_bounds__(256) void k_layer_gemm(
    const bf16* __restrict__ Ab, const bf16* __restrict__ Hb,
    const bf16* __restrict__ Wr, const bf16* __restrict__ Wo,
    const float* __restrict__ bias, float* __restrict__ out,
    float* __restrict__ sums, int M) {
  __shared__ __align__(16) bf16 As[128 * 40];  // stride 40 (80B): 2-way bank alias = free
  __shared__ __align__(16) bf16 Bs[128 * 40];
  __shared__ float bsum[128], bsq[128];
  int tid = threadIdx.x;
  int wave = tid >> 6, lane = tid & 63;
  int wm = wave & 1, wn = wave >> 1;
  int m0 = blockIdx.x * 128, c0 = blockIdx.y * 128;
  if (tid < 128) { bsum[tid] = 0.f; bsq[tid] = 0.f; }
  int l15 = lane & 15, lq = lane >> 4;
  int kq = lq * 8;
  f32x4 acc[4][4] = {};
  for (int phase = 0; phase < 2; ++phase) {
    const bf16* A = phase ? Hb : Ab;
    const bf16* B = phase ? Wo : Wr;
    for (int kt = 0; kt < HID; kt += 32) {
#pragma unroll
      for (int it = 0; it < 2; ++it) {
        int ch = tid + it * 256;           // 512 chunks of 16B
        int row = ch >> 2, q = ch & 3;
        int gr = m0 + row;
        bf16x8 v = {};
        if (gr < M) v = *(const bf16x8*)(A + (size_t)gr * HID + kt + q * 8);
        *(bf16x8*)(&As[row * 40 + q * 8]) = v;
        bf16x8 w = *(const bf16x8*)(B + (size_t)(c0 + row) * HID + kt + q * 8);
        *(bf16x8*)(&Bs[row * 40 + q * 8]) = w;
      }
      __syncthreads();
      bf16x8 af[4], bfv[4];
#pragma unroll
      for (int i = 0; i < 4; ++i)
        af[i] = *(const bf16x8*)(&As[(wm * 64 + i * 16 + l15) * 40 + kq]);
#pragma unroll
      for (int j = 0; j < 4; ++j)
        bfv[j] = *(const bf16x8*)(&Bs[(wn * 64 + j * 16 + l15) * 40 + kq]);
#pragma unroll
      for (int i = 0; i < 4; ++i)
#pragma unroll
        for (int j = 0; j < 4; ++j)
          acc[i][j] = __builtin_amdgcn_mfma_f32_16x16x32_bf16(af[i], bfv[j], acc[i][j], 0, 0, 0);
      __syncthreads();
    }
  }
  // epilogue: bias, store, per-channel sum/sumsq (C/D layout: col=lane&15, row=quad*4+reg)
#pragma unroll
  for (int i = 0; i < 4; ++i) {
    int row = wm * 64 + i * 16 + lq * 4;
#pragma unroll
    for (int j = 0; j < 4; ++j) {
      int col = wn * 64 + j * 16 + l15;
      int gc = c0 + col;
      float bv = bias[gc];
      float s = 0.f, sq = 0.f;
#pragma unroll
      for (int r = 0; r < 4; ++r) {
        int gr = m0 + row + r;
        if (gr < M) {
          float v = acc[i][j][r] + bv;
          out[(size_t)gr * HID + gc] = v;
          s += v;
          sq += v * v;
        }
      }
      atomicAdd(&bsum[col], s);
      atomicAdd(&bsq[col], sq);
    }
  }
  __syncthreads();
  if (tid < 128) {
    atomicAdd(&sums[c0 + tid], bsum[tid]);
    atomicAdd(&sums[256 + c0 + tid], bsq[tid]);
  }
}

// ---------------- BN finalize + ReLU + residual ----------------

__global__ __launch_bounds__(256) void k_bn_residual(
    const float* __restrict__ out, float* __restrict__ h, bf16* __restrict__ hb,
    const float* __restrict__ sums, const float* __restrict__ gamma,
    const float* __restrict__ beta, int N, float invN) {
  int c = threadIdx.x;
  float mean = sums[c] * invN;
  float var = sums[256 + c] * invN - mean * mean;
  float istd = rsqrtf(var + 1e-5f);
  float a = istd * gamma[c];
  float b = beta[c] - mean * a;
  int r0 = blockIdx.x * 64;
  int r1 = min(r0 + 64, N);
  for (int r = r0; r < r1; ++r) {
    size_t idx = (size_t)r * HID + c;
    float y = fmaf(out[idx], a, b);
    y = fmaxf(y, 0.f);
    float hn = h[idx] + y;
    h[idx] = hn;
    hb[idx] = (bf16)hn;
  }
}

// ---------------- fused edge MLP ----------------
// 64 edges/block, 4 waves. z1/z2 live in LDS only. A chunks staged per 32-k slice.

__global__ __launch_bounds__(256) void k_edge_mlp(
    const bf16* __restrict__ hb, const int* __restrict__ eidx,
    const bf16* __restrict__ W1b, const float* __restrict__ b1v,
    const bf16* __restrict__ W2b, const float* __restrict__ b2v,
    const float* __restrict__ w3, const float* __restrict__ b3,
    float* __restrict__ outp, int E) {
  __shared__ __align__(16) bf16 As[64 * 40];
  __shared__ __align__(16) bf16 z1s[64 * 264];
  __shared__ __align__(16) bf16 z2s[64 * 264];
  __shared__ int nd[128];  // [0..63]=src, [64..127]=dst
  __shared__ float red[256];
  int tid = threadIdx.x;
  int e0 = blockIdx.x * 64;
  if (tid < 128) {
    int e = e0 + (tid & 63);
    int which = tid >> 6;
    nd[tid] = (e < E) ? eidx[(size_t)which * E + e] : 0;
  }
  __syncthreads();
  int wave = tid >> 6, lane = tid & 63;
  int l15 = lane & 15, lq = lane >> 4;
  int kq = lq * 8;

  // ---- z1 = relu(cat(h[src],h[dst]) @ W1^T + b1), K=512 ----
  f32x4 acc[4][4] = {};
  for (int ks = 0; ks < 512; ks += 32) {
    {
      int r = tid >> 2, q = tid & 3;  // 64 rows x 4 quads
      int node = nd[(ks >> 8) * 64 + r];
      bf16x8 v = *(const bf16x8*)(hb + (size_t)node * HID + (ks & 255) + q * 8);
      *(bf16x8*)(&As[r * 40 + q * 8]) = v;
    }
    __syncthreads();
    bf16x8 af[4];
#pragma unroll
    for (int i = 0; i < 4; ++i)
      af[i] = *(const bf16x8*)(&As[(i * 16 + l15) * 40 + kq]);
#pragma unroll
    for (int j = 0; j < 4; ++j) {
      int col = wave * 64 + j * 16 + l15;
      bf16x8 bv = *(const bf16x8*)(W1b + (size_t)col * 512 + ks + kq);
#pragma unroll
      for (int i = 0; i < 4; ++i)
        acc[i][j] = __builtin_amdgcn_mfma_f32_16x16x32_bf16(af[i], bv, acc[i][j], 0, 0, 0);
    }
    __syncthreads();
  }
#pragma unroll
  for (int j = 0; j < 4; ++j) {
    int col = wave * 64 + j * 16 + l15;
    float bias = b1v[col];
#pragma unroll
    for (int i = 0; i < 4; ++i) {
      int row = i * 16 + lq * 4;
#pragma unroll
      for (int r = 0; r < 4; ++r)
        z1s[(row + r) * 264 + col] = (bf16)fmaxf(acc[i][j][r] + bias, 0.f);
    }
  }
  __syncthreads();

  // ---- z2 = relu(z1 @ W2^T + b2), K=256 ----
  f32x4 acc2[4][4] = {};
  for (int ks = 0; ks < 256; ks += 32) {
    bf16x8 af[4];
#pragma unroll
    for (int i = 0; i < 4; ++i)
      af[i] = *(const bf16x8*)(&z1s[(i * 16 + l15) * 264 + ks + kq]);
#pragma unroll
    for (int j = 0; j < 4; ++j) {
      int col = wave * 64 + j * 16 + l15;
      bf16x8 bv = *(const bf16x8*)(W2b + (size_t)col * HID + ks + kq);
#pragma unroll
      for (int i = 0; i < 4; ++i)
        acc2[i][j] = __builtin_amdgcn_mfma_f32_16x16x32_bf16(af[i], bv, acc2[i][j], 0, 0, 0);
    }
  }
#pragma unroll
  for (int j = 0; j < 4; ++j) {
    int col = wave * 64 + j * 16 + l15;
    float bias = b2v[col];
#pragma unroll
    for (int i = 0; i < 4; ++i) {
      int row = i * 16 + lq * 4;
#pragma unroll
      for (int r = 0; r < 4; ++r)
        z2s[(row + r) * 264 + col] = (bf16)fmaxf(acc2[i][j][r] + bias, 0.f);
    }
  }
  __syncthreads();

  // ---- logit = z2 . w3 + b3 ; sigmoid ----
  {
    int e = tid >> 2, q = tid & 3;
    float s = 0.f;
    int cb = q * 64;
#pragma unroll 8
    for (int c = 0; c < 64; ++c)
      s += (float)z2s[e * 264 + cb + c] * w3[cb + c];
    red[tid] = s;
  }
  __syncthreads();
  if (tid < 64) {
    float logit = red[tid * 4] + red[tid * 4 + 1] + red[tid * 4 + 2] + red[tid * 4 + 3] + b3[0];
    int e = e0 + tid;
    if (e < E) outp[e] = 1.f / (1.f + expf(-logit));
  }
}

// ---------------- host ----------------

static inline size_t align256(size_t x) { return (x + 255) & ~(size_t)255; }

extern "C" void kernel_launch(void* const* d_in, const int* in_sizes, int n_in,
                              void* d_out, int out_size, void* d_ws, size_t ws_size,
                              hipStream_t stream) {
  const float* x     = (const float*)d_in[0];
  const int*   ei    = (const int*)d_in[1];
  const float* Win   = (const float*)d_in[2];
  const float* Wrel  = (const float*)d_in[3];
  const float* brel  = (const float*)d_in[4];
  const float* Wroot = (const float*)d_in[5];
  const float* gamma = (const float*)d_in[6];
  const float* beta  = (const float*)d_in[7];
  const float* W1    = (const float*)d_in[8];
  const float* b1    = (const float*)d_in[9];
  const float* W2    = (const float*)d_in[10];
  const float* b2    = (const float*)d_in[11];
  const float* W3    = (const float*)d_in[12];
  const float* b3    = (const float*)d_in[13];

  const int N = in_sizes[0] / 2;              // 50000
  const int E = in_sizes[1] / 2;              // 500000
  const int L = in_sizes[3] / (HID * HID);    // 15

  char* p = (char*)d_ws;
  auto alloc = [&](size_t bytes) { char* r = p; p += align256(bytes); return r; };
  float* h     = (float*)alloc((size_t)N * HID * 4);
  float* outb  = (float*)alloc((size_t)N * HID * 4);
  bf16*  hb    = (bf16*)alloc((size_t)N * HID * 2);
  bf16*  aggb  = (bf16*)alloc((size_t)N * HID * 2);
  bf16*  Wrelb = (bf16*)alloc((size_t)L * HID * HID * 2);
  bf16*  Wrootb= (bf16*)alloc((size_t)L * HID * HID * 2);
  bf16*  W1b   = (bf16*)alloc((size_t)HID * 2 * HID * 2);
  bf16*  W2b   = (bf16*)alloc((size_t)HID * HID * 2);
  int*   deg   = (int*)alloc((size_t)N * 4);
  int*   offs  = (int*)alloc((size_t)(N + 1) * 4);
  int*   cursor= (int*)alloc((size_t)N * 4);
  int*   csr   = (int*)alloc((size_t)E * 4);
  int*   bsums = (int*)alloc(64 * 4);
  float* sums  = (float*)alloc(512 * 4);
  (void)ws_size; (void)n_in; (void)out_size;

  const int nb = (N + 1023) / 1024;

  // CSR build
  k_zero_i32<<<(N + 255) / 256, 256, 0, stream>>>(deg, N);
  k_hist<<<(E + 255) / 256, 256, 0, stream>>>(ei, deg, E);
  k_scan1<<<nb, 1024, 0, stream>>>(deg, offs, bsums, N);
  k_scan2<<<1, 64, 0, stream>>>(bsums, nb);
  k_scan3<<<nb, 1024, 0, stream>>>(offs, cursor, bsums, N, E);
  k_fill<<<(E + 255) / 256, 256, 0, stream>>>(ei, cursor, csr, E);

  // weights -> bf16
  k_cvt<<<(L * HID * HID + 255) / 256, 256, 0, stream>>>(Wrel, Wrelb, L * HID * HID);
  k_cvt<<<(L * HID * HID + 255) / 256, 256, 0, stream>>>(Wroot, Wrootb, L * HID * HID);
  k_cvt<<<(2 * HID * HID + 255) / 256, 256, 0, stream>>>(W1, W1b, 2 * HID * HID);
  k_cvt<<<(HID * HID + 255) / 256, 256, 0, stream>>>(W2, W2b, HID * HID);

  // input fc
  k_input_fc<<<N, 256, 0, stream>>>(x, Win, h, hb, N);

  // layers
  const float invN = 1.0f / (float)N;
  for (int l = 0; l < L; ++l) {
    k_aggregate<<<(N + 3) / 4, 256, 0, stream>>>(hb, offs, csr, aggb, sums, N);
    k_layer_gemm<<<dim3((N + 127) / 128, 2), 256, 0, stream>>>(
        aggb, hb, Wrelb + (size_t)l * HID * HID, Wrootb + (size_t)l * HID * HID,
        brel + (size_t)l * HID, outb, sums, N);
    k_bn_residual<<<(N + 63) / 64, 256, 0, stream>>>(
        outb, h, hb, sums, gamma + (size_t)l * HID, beta + (size_t)l * HID, N, invN);
  }

  // edge MLP
  k_edge_mlp<<<(E + 63) / 64, 256, 0, stream>>>(
      hb, ei, W1b, b1, W2b, b2, W3, b3, (float*)d_out, E);
}

// Round 2
// 2432.598 us; speedup vs baseline: 1.2344x; 1.2344x over previous
//
#include <hip/hip_runtime.h>
#include <cstdint>
#include <cstddef>

#define HID 256

typedef __bf16 bf16;
typedef __bf16 bf16x4 __attribute__((ext_vector_type(4)));
typedef __bf16 bf16x8 __attribute__((ext_vector_type(8)));
typedef float f32x4 __attribute__((ext_vector_type(4)));

// ---------------- CSR build ----------------

__global__ void k_zero_i32(int* __restrict__ p, int n) {
  int i = blockIdx.x * blockDim.x + threadIdx.x;
  if (i < n) p[i] = 0;
}

__global__ void k_hist(const int* __restrict__ ei, int* __restrict__ deg, int E) {
  int i = blockIdx.x * blockDim.x + threadIdx.x;
  if (i < E) atomicAdd(&deg[ei[E + i]], 1);  // dst = ei[E + i]
}

__global__ void k_scan1(const int* __restrict__ deg, int* __restrict__ offs,
                        int* __restrict__ bsums, int n) {
  __shared__ int sh[1024];
  int i = blockIdx.x * 1024 + threadIdx.x;
  int v = (i < n) ? deg[i] : 0;
  sh[threadIdx.x] = v;
  __syncthreads();
  for (int d = 1; d < 1024; d <<= 1) {
    int t = (threadIdx.x >= (unsigned)d) ? sh[threadIdx.x - d] : 0;
    __syncthreads();
    sh[threadIdx.x] += t;
    __syncthreads();
  }
  if (i < n) offs[i] = sh[threadIdx.x] - v;  // exclusive within block
  if (threadIdx.x == 1023) bsums[blockIdx.x] = sh[1023];
}

__global__ void k_scan2(int* __restrict__ bsums, int nb) {
  if (threadIdx.x == 0 && blockIdx.x == 0) {
    int run = 0;
    for (int b = 0; b < nb; ++b) { int t = bsums[b]; bsums[b] = run; run += t; }
  }
}

__global__ void k_scan3(int* __restrict__ offs, int* __restrict__ cursor,
                        const int* __restrict__ bsums, int n, int E) {
  int i = blockIdx.x * 1024 + threadIdx.x;
  if (i < n) { int o = offs[i] + bsums[blockIdx.x]; offs[i] = o; cursor[i] = o; }
  if (i == 0) offs[n] = E;
}

__global__ void k_fill(const int* __restrict__ ei, int* __restrict__ cursor,
                       int* __restrict__ csr, int E) {
  int i = blockIdx.x * blockDim.x + threadIdx.x;
  if (i < E) {
    int pos = atomicAdd(&cursor[ei[E + i]], 1);
    csr[pos] = ei[i];  // store src, keyed by dst
  }
}

// ---------------- weight convert + input fc ----------------

__global__ void k_cvt(const float* __restrict__ s, bf16* __restrict__ d, int n) {
  int i = blockIdx.x * blockDim.x + threadIdx.x;
  if (i < n) d[i] = (bf16)s[i];
}

__global__ void k_input_fc(const float* __restrict__ x, const float* __restrict__ Win,
                           float* __restrict__ h, bf16* __restrict__ hb, int N) {
  int i = blockIdx.x;
  int c = threadIdx.x;
  float v = x[2 * i] * Win[2 * c] + x[2 * i + 1] * Win[2 * c + 1];
  size_t idx = (size_t)i * HID + c;
  h[idx] = v;
  hb[idx] = (bf16)v;
}

// ---------------- aggregation: 2 nodes per wave, 32 lanes x bf16x8 gathers ----------------

__global__ __launch_bounds__(256) void k_aggregate(
    const bf16* __restrict__ hb, const int* __restrict__ offs,
    const int* __restrict__ csr, bf16* __restrict__ aggb,
    float* __restrict__ sums, int N) {
  // block 0 zeroes the BN-stat accumulators for the following GEMM
  if (blockIdx.x == 0 && threadIdx.x < 256) {
    sums[threadIdx.x] = 0.f;
    sums[256 + threadIdx.x] = 0.f;
  }
  int gwave = (int)((blockIdx.x * blockDim.x + threadIdx.x) >> 6);
  int lane = threadIdx.x & 63;
  int node = gwave * 2 + (lane >> 5);
  int l32 = lane & 31;
  if (node >= N) return;
  int e0 = offs[node], e1 = offs[node + 1];
  float a[8] = {};
  int e = e0;
  for (; e + 1 < e1; e += 2) {  // 2 independent 16B gathers in flight
    int s0 = csr[e], s1 = csr[e + 1];
    bf16x8 v0 = *(const bf16x8*)(hb + (size_t)s0 * HID + l32 * 8);
    bf16x8 v1 = *(const bf16x8*)(hb + (size_t)s1 * HID + l32 * 8);
#pragma unroll
    for (int k = 0; k < 8; ++k) a[k] += (float)v0[k] + (float)v1[k];
  }
  if (e < e1) {
    int s0 = csr[e];
    bf16x8 v0 = *(const bf16x8*)(hb + (size_t)s0 * HID + l32 * 8);
#pragma unroll
    for (int k = 0; k < 8; ++k) a[k] += (float)v0[k];
  }
  bf16x8 o;
#pragma unroll
  for (int k = 0; k < 8; ++k) o[k] = (bf16)a[k];
  *(bf16x8*)(aggb + (size_t)node * HID + l32 * 8) = o;
}

// ---------------- fused layer GEMM: out = agg@Wr^T + h@Wo^T + br, + BN stats ----------------
// 128x128 tile, 4 waves (2x2), 16x16x32 bf16 MFMA, K = 2 phases x 256.
// out stored as bf16; BN stats shuffle-reduced before LDS atomics.

__global__ __launch_bounds__(256) void k_layer_gemm(
    const bf16* __restrict__ Ab, const bf16* __restrict__ Hb,
    const bf16* __restrict__ Wr, const bf16* __restrict__ Wo,
    const float* __restrict__ bias, bf16* __restrict__ out,
    float* __restrict__ sums, int M) {
  __shared__ __align__(16) bf16 As[128 * 40];  // stride 40 (80B): 2-way bank alias = free
  __shared__ __align__(16) bf16 Bs[128 * 40];
  __shared__ float bsum[128], bsq[128];
  int tid = threadIdx.x;
  int wave = tid >> 6, lane = tid & 63;
  int wm = wave & 1, wn = wave >> 1;
  int m0 = blockIdx.x * 128, c0 = blockIdx.y * 128;
  if (tid < 128) { bsum[tid] = 0.f; bsq[tid] = 0.f; }
  int l15 = lane & 15, lq = lane >> 4;
  int kq = lq * 8;
  f32x4 acc[4][4] = {};
  for (int phase = 0; phase < 2; ++phase) {
    const bf16* A = phase ? Hb : Ab;
    const bf16* B = phase ? Wo : Wr;
    for (int kt = 0; kt < HID; kt += 32) {
#pragma unroll
      for (int it = 0; it < 2; ++it) {
        int ch = tid + it * 256;           // 512 chunks of 16B
        int row = ch >> 2, q = ch & 3;
        int gr = m0 + row;
        bf16x8 v = {};
        if (gr < M) v = *(const bf16x8*)(A + (size_t)gr * HID + kt + q * 8);
        *(bf16x8*)(&As[row * 40 + q * 8]) = v;
        bf16x8 w = *(const bf16x8*)(B + (size_t)(c0 + row) * HID + kt + q * 8);
        *(bf16x8*)(&Bs[row * 40 + q * 8]) = w;
      }
      __syncthreads();
      bf16x8 af[4], bfv[4];
#pragma unroll
      for (int i = 0; i < 4; ++i)
        af[i] = *(const bf16x8*)(&As[(wm * 64 + i * 16 + l15) * 40 + kq]);
#pragma unroll
      for (int j = 0; j < 4; ++j)
        bfv[j] = *(const bf16x8*)(&Bs[(wn * 64 + j * 16 + l15) * 40 + kq]);
#pragma unroll
      for (int i = 0; i < 4; ++i)
#pragma unroll
        for (int j = 0; j < 4; ++j)
          acc[i][j] = __builtin_amdgcn_mfma_f32_16x16x32_bf16(af[i], bfv[j], acc[i][j], 0, 0, 0);
      __syncthreads();
    }
  }
  // epilogue: bias, bf16 store, per-channel sum/sumsq.
  // C/D layout: col=lane&15, row=(lane>>4)*4+reg. Shuffle-reduce over lq (lanes ^16,^32)
  // so only 16 lanes/wave issue contention-free LDS atomics.
#pragma unroll
  for (int i = 0; i < 4; ++i) {
    int row = wm * 64 + i * 16 + lq * 4;
#pragma unroll
    for (int j = 0; j < 4; ++j) {
      int col = wn * 64 + j * 16 + l15;
      int gc = c0 + col;
      float bv = bias[gc];
      float s = 0.f, sq = 0.f;
#pragma unroll
      for (int r = 0; r < 4; ++r) {
        int gr = m0 + row + r;
        if (gr < M) {
          float v = acc[i][j][r] + bv;
          out[(size_t)gr * HID + gc] = (bf16)v;
          s += v;
          sq += v * v;
        }
      }
      s += __shfl_xor(s, 16, 64);  s += __shfl_xor(s, 32, 64);
      sq += __shfl_xor(sq, 16, 64); sq += __shfl_xor(sq, 32, 64);
      if (lq == 0) {
        atomicAdd(&bsum[col], s);
        atomicAdd(&bsq[col], sq);
      }
    }
  }
  __syncthreads();
  if (tid < 128) {
    atomicAdd(&sums[c0 + tid], bsum[tid]);
    atomicAdd(&sums[256 + c0 + tid], bsq[tid]);
  }
}

// ---------------- BN finalize + ReLU + residual (vectorized) ----------------
// block: 128 rows x 256 ch; thread: 8 channels x 16 rows.

__global__ __launch_bounds__(256) void k_bn_residual(
    const bf16* __restrict__ outb, float* __restrict__ h, bf16* __restrict__ hb,
    const float* __restrict__ sums, const float* __restrict__ gamma,
    const float* __restrict__ beta, int N, float invN) {
  int t = threadIdx.x;
  int cg = (t & 31) * 8;
  int r0 = blockIdx.x * 128 + (t >> 5) * 16;
  float a[8], b[8];
#pragma unroll
  for (int k = 0; k < 8; ++k) {
    int c = cg + k;
    float mean = sums[c] * invN;
    float var = sums[256 + c] * invN - mean * mean;
    float istd = rsqrtf(var + 1e-5f);
    a[k] = istd * gamma[c];
    b[k] = fmaf(-mean, a[k], beta[c]);
  }
  int r1 = min(r0 + 16, N);
  for (int r = r0; r < r1; ++r) {
    size_t idx = (size_t)r * HID + cg;
    bf16x8 ov = *(const bf16x8*)(outb + idx);
    float4 h0 = *(const float4*)(h + idx);
    float4 h1 = *(const float4*)(h + idx + 4);
    float hn[8];
#pragma unroll
    for (int k = 0; k < 8; ++k) {
      float y = fmaf((float)ov[k], a[k], b[k]);
      y = fmaxf(y, 0.f);
      float hv = (k < 4) ? ((const float*)&h0)[k] : ((const float*)&h1)[k - 4];
      hn[k] = hv + y;
    }
    *(float4*)(h + idx)     = make_float4(hn[0], hn[1], hn[2], hn[3]);
    *(float4*)(h + idx + 4) = make_float4(hn[4], hn[5], hn[6], hn[7]);
    bf16x8 o;
#pragma unroll
    for (int k = 0; k < 8; ++k) o[k] = (bf16)hn[k];
    *(bf16x8*)(hb + idx) = o;
  }
}

// ---------------- fused edge MLP ----------------
// 64 edges/block, 4 waves. z1 round-trips LDS (layout transform); z2 stays in
// registers — dotted with w3 straight from the accumulator, shuffle-reduced.

__global__ __launch_bounds__(256) void k_edge_mlp(
    const bf16* __restrict__ hb, const int* __restrict__ eidx,
    const bf16* __restrict__ W1b, const float* __restrict__ b1v,
    const bf16* __restrict__ W2b, const float* __restrict__ b2v,
    const float* __restrict__ w3, const float* __restrict__ b3,
    float* __restrict__ outp, int E) {
  __shared__ __align__(16) bf16 As[64 * 40];    // 5 KB
  __shared__ __align__(16) bf16 z1s[64 * 264];  // 33.8 KB
  __shared__ int nd[128];  // [0..63]=src, [64..127]=dst
  __shared__ float red[64];
  int tid = threadIdx.x;
  int e0 = blockIdx.x * 64;
  if (tid < 128) {
    int e = e0 + (tid & 63);
    int which = tid >> 6;
    nd[tid] = (e < E) ? eidx[(size_t)which * E + e] : 0;
  }
  if (tid < 64) red[tid] = 0.f;
  __syncthreads();
  int wave = tid >> 6, lane = tid & 63;
  int l15 = lane & 15, lq = lane >> 4;
  int kq = lq * 8;

  // ---- z1 = relu(cat(h[src],h[dst]) @ W1^T + b1), K=512 ----
  f32x4 acc[4][4] = {};
  for (int ks = 0; ks < 512; ks += 32) {
    {
      int r = tid >> 2, q = tid & 3;  // 64 rows x 4 quads
      int node = nd[(ks >> 8) * 64 + r];
      bf16x8 v = *(const bf16x8*)(hb + (size_t)node * HID + (ks & 255) + q * 8);
      *(bf16x8*)(&As[r * 40 + q * 8]) = v;
    }
    __syncthreads();
    bf16x8 af[4];
#pragma unroll
    for (int i = 0; i < 4; ++i)
      af[i] = *(const bf16x8*)(&As[(i * 16 + l15) * 40 + kq]);
#pragma unroll
    for (int j = 0; j < 4; ++j) {
      int col = wave * 64 + j * 16 + l15;
      bf16x8 bv = *(const bf16x8*)(W1b + (size_t)col * 512 + ks + kq);
#pragma unroll
      for (int i = 0; i < 4; ++i)
        acc[i][j] = __builtin_amdgcn_mfma_f32_16x16x32_bf16(af[i], bv, acc[i][j], 0, 0, 0);
    }
    __syncthreads();
  }
#pragma unroll
  for (int j = 0; j < 4; ++j) {
    int col = wave * 64 + j * 16 + l15;
    float bias = b1v[col];
#pragma unroll
    for (int i = 0; i < 4; ++i) {
      int row = i * 16 + lq * 4;
#pragma unroll
      for (int r = 0; r < 4; ++r)
        z1s[(row + r) * 264 + col] = (bf16)fmaxf(acc[i][j][r] + bias, 0.f);
    }
  }
  __syncthreads();

  // ---- z2 = relu(z1 @ W2^T + b2), K=256 — accumulators stay in registers ----
  f32x4 acc2[4][4] = {};
  for (int ks = 0; ks < 256; ks += 32) {
    bf16x8 af[4];
#pragma unroll
    for (int i = 0; i < 4; ++i)
      af[i] = *(const bf16x8*)(&z1s[(i * 16 + l15) * 264 + ks + kq]);
#pragma unroll
    for (int j = 0; j < 4; ++j) {
      int col = wave * 64 + j * 16 + l15;
      bf16x8 bv = *(const bf16x8*)(W2b + (size_t)col * HID + ks + kq);
#pragma unroll
      for (int i = 0; i < 4; ++i)
        acc2[i][j] = __builtin_amdgcn_mfma_f32_16x16x32_bf16(af[i], bv, acc2[i][j], 0, 0, 0);
    }
  }

  // ---- logit = relu(z2).w3 directly from C-layout registers ----
  // lane holds rows {i*16 + lq*4 + r}, cols {wave*64 + j*16 + l15}.
  float s[4][4];
#pragma unroll
  for (int i = 0; i < 4; ++i)
#pragma unroll
    for (int r = 0; r < 4; ++r) s[i][r] = 0.f;
#pragma unroll
  for (int j = 0; j < 4; ++j) {
    int col = wave * 64 + j * 16 + l15;
    float w3v = w3[col];
    float b2c = b2v[col];
#pragma unroll
    for (int i = 0; i < 4; ++i)
#pragma unroll
      for (int r = 0; r < 4; ++r)
        s[i][r] = fmaf(fmaxf(acc2[i][j][r] + b2c, 0.f), w3v, s[i][r]);
  }
  // butterfly over l15 (bits 0..3): sum across the 16 col-lanes
#pragma unroll
  for (int d = 1; d < 16; d <<= 1) {
#pragma unroll
    for (int i = 0; i < 4; ++i)
#pragma unroll
      for (int r = 0; r < 4; ++r)
        s[i][r] += __shfl_xor(s[i][r], d, 64);
  }
  if (l15 == 0) {
#pragma unroll
    for (int i = 0; i < 4; ++i)
#pragma unroll
      for (int r = 0; r < 4; ++r)
        atomicAdd(&red[i * 16 + lq * 4 + r], s[i][r]);
  }
  __syncthreads();
  if (tid < 64) {
    int e = e0 + tid;
    if (e < E) {
      float logit = red[tid] + b3[0];
      outp[e] = 1.f / (1.f + expf(-logit));
    }
  }
}

// ---------------- host ----------------

static inline size_t align256(size_t x) { return (x + 255) & ~(size_t)255; }

extern "C" void kernel_launch(void* const* d_in, const int* in_sizes, int n_in,
                              void* d_out, int out_size, void* d_ws, size_t ws_size,
                              hipStream_t stream) {
  const float* x     = (const float*)d_in[0];
  const int*   ei    = (const int*)d_in[1];
  const float* Win   = (const float*)d_in[2];
  const float* Wrel  = (const float*)d_in[3];
  const float* brel  = (const float*)d_in[4];
  const float* Wroot = (const float*)d_in[5];
  const float* gamma = (const float*)d_in[6];
  const float* beta  = (const float*)d_in[7];
  const float* W1    = (const float*)d_in[8];
  const float* b1    = (const float*)d_in[9];
  const float* W2    = (const float*)d_in[10];
  const float* b2    = (const float*)d_in[11];
  const float* W3    = (const float*)d_in[12];
  const float* b3    = (const float*)d_in[13];

  const int N = in_sizes[0] / 2;              // 50000
  const int E = in_sizes[1] / 2;              // 500000
  const int L = in_sizes[3] / (HID * HID);    // 15

  char* p = (char*)d_ws;
  auto alloc = [&](size_t bytes) { char* r = p; p += align256(bytes); return r; };
  float* h     = (float*)alloc((size_t)N * HID * 4);
  bf16*  outb  = (bf16*)alloc((size_t)N * HID * 2);
  bf16*  hb    = (bf16*)alloc((size_t)N * HID * 2);
  bf16*  aggb  = (bf16*)alloc((size_t)N * HID * 2);
  bf16*  Wrelb = (bf16*)alloc((size_t)L * HID * HID * 2);
  bf16*  Wrootb= (bf16*)alloc((size_t)L * HID * HID * 2);
  bf16*  W1b   = (bf16*)alloc((size_t)HID * 2 * HID * 2);
  bf16*  W2b   = (bf16*)alloc((size_t)HID * HID * 2);
  int*   deg   = (int*)alloc((size_t)N * 4);
  int*   offs  = (int*)alloc((size_t)(N + 1) * 4);
  int*   cursor= (int*)alloc((size_t)N * 4);
  int*   csr   = (int*)alloc((size_t)E * 4);
  int*   bsums = (int*)alloc(64 * 4);
  float* sums  = (float*)alloc(512 * 4);
  (void)ws_size; (void)n_in; (void)out_size;

  const int nb = (N + 1023) / 1024;

  // CSR build
  k_zero_i32<<<(N + 255) / 256, 256, 0, stream>>>(deg, N);
  k_hist<<<(E + 255) / 256, 256, 0, stream>>>(ei, deg, E);
  k_scan1<<<nb, 1024, 0, stream>>>(deg, offs, bsums, N);
  k_scan2<<<1, 64, 0, stream>>>(bsums, nb);
  k_scan3<<<nb, 1024, 0, stream>>>(offs, cursor, bsums, N, E);
  k_fill<<<(E + 255) / 256, 256, 0, stream>>>(ei, cursor, csr, E);

  // weights -> bf16
  k_cvt<<<(L * HID * HID + 255) / 256, 256, 0, stream>>>(Wrel, Wrelb, L * HID * HID);
  k_cvt<<<(L * HID * HID + 255) / 256, 256, 0, stream>>>(Wroot, Wrootb, L * HID * HID);
  k_cvt<<<(2 * HID * HID + 255) / 256, 256, 0, stream>>>(W1, W1b, 2 * HID * HID);
  k_cvt<<<(HID * HID + 255) / 256, 256, 0, stream>>>(W2, W2b, HID * HID);

  // input fc
  k_input_fc<<<N, 256, 0, stream>>>(x, Win, h, hb, N);

  // layers
  const float invN = 1.0f / (float)N;
  for (int l = 0; l < L; ++l) {
    k_aggregate<<<(N + 7) / 8, 256, 0, stream>>>(hb, offs, csr, aggb, sums, N);
    k_layer_gemm<<<dim3((N + 127) / 128, 2), 256, 0, stream>>>(
        aggb, hb, Wrelb + (size_t)l * HID * HID, Wrootb + (size_t)l * HID * HID,
        brel + (size_t)l * HID, outb, sums, N);
    k_bn_residual<<<(N + 127) / 128, 256, 0, stream>>>(
        outb, h, hb, sums, gamma + (size_t)l * HID, beta + (size_t)l * HID, N, invN);
  }

  // edge MLP
  k_edge_mlp<<<(E + 63) / 64, 256, 0, stream>>>(
      hb, ei, W1b, b1, W2b, b2, W3, b3, (float*)d_out, E);
}